// Round 18
// baseline (150.687 us; speedup 1.0000x reference)
//
#include <hip/hip_runtime.h>

typedef __attribute__((ext_vector_type(4))) float f32x4;
typedef __attribute__((ext_vector_type(16))) float f32x16;
typedef __attribute__((ext_vector_type(8))) __bf16 bf16x8;
typedef __attribute__((ext_vector_type(4))) unsigned short u16x4;
typedef __attribute__((ext_vector_type(2))) unsigned int u32x2;

#define DEVI static __device__ __forceinline__

DEVI unsigned short bf16_bits(float f) {
  __bf16 h = (__bf16)f;
  return __builtin_bit_cast(unsigned short, h);
}

DEVI float bf16_f32(__bf16 u) { return (float)u; }

DEVI void gl_lds16(const void* g, void* l) {
  __builtin_amdgcn_global_load_lds(
      (const __attribute__((address_space(1))) void*)g,
      (__attribute__((address_space(3))) void*)l, 16, 0, 0);
}

DEVI f32x4 mfma16x16(bf16x8 a, bf16x8 b, f32x4 c) {
  return __builtin_amdgcn_mfma_f32_16x16x32_bf16(a, b, c, 0, 0, 0);
}

DEVI f32x16 mfma32(bf16x8 a, bf16x8 b, f32x16 c) {
  return __builtin_amdgcn_mfma_f32_32x32x16_bf16(a, b, c, 0, 0, 0);
}

DEVI unsigned cvtpk_bf16(float lo, float hi2) {
  unsigned r;
  asm("v_cvt_pk_bf16_f32 %0, %1, %2" : "=v"(r) : "v"(lo), "v"(hi2));
  return r;
}

// NOTE (r3/r4): never call with two copies of one value (allocator coalesces).
// NOTE (r15/r16): MFMA whose ONLY inputs are INLINEASM-built fragments gave
// schedule-dependent wrong results in two placements — abandoned.
DEVI void pl32swap(unsigned& a, unsigned& b) {
  asm volatile("s_nop 1\nv_permlane32_swap_b32 %0, %1\ns_nop 1"
               : "+v"(a), "+v"(b));
}

#define WAITVM0 asm volatile("s_waitcnt vmcnt(0)" ::: "memory")

// ---------------------------------------------------------------- prep
// Fused ln (blocks 0..4095) + w_qkv transpose (4096..4863) + w_out
// transpose (4864..5119). r13/r14/r17-verified.
__global__ __launch_bounds__(256) void prep_kernel(
    const float* __restrict__ x, const float* __restrict__ gamma,
    const float* __restrict__ beta, __bf16* __restrict__ xn,
    const float* __restrict__ w_qkv, __bf16* __restrict__ wqkvT,
    const float* __restrict__ w_out, __bf16* __restrict__ woutT) {
  __shared__ float tile[64][65];
  __shared__ float red[8];
  int blk = blockIdx.x;
  int t = threadIdx.x;
  if (blk < 4096) {
    int row = blk;
    float4 v = ((const float4*)(x + (size_t)row * 1024))[t];
    float s = v.x + v.y + v.z + v.w;
    float sq = v.x * v.x + v.y * v.y + v.z * v.z + v.w * v.w;
#pragma unroll
    for (int off = 32; off > 0; off >>= 1) {
      s += __shfl_down(s, off);
      sq += __shfl_down(sq, off);
    }
    int w = t >> 6, ln = t & 63;
    if (ln == 0) { red[w] = s; red[4 + w] = sq; }
    __syncthreads();
    s = red[0] + red[1] + red[2] + red[3];
    sq = red[4] + red[5] + red[6] + red[7];
    float mu = s * (1.0f / 1024.0f);
    float var = sq * (1.0f / 1024.0f) - mu * mu;
    float rstd = rsqrtf(var + 1e-5f);
    float4 g = ((const float4*)gamma)[t];
    float4 b = ((const float4*)beta)[t];
    u16x4 o;
    o[0] = bf16_bits((v.x - mu) * rstd * g.x + b.x);
    o[1] = bf16_bits((v.y - mu) * rstd * g.y + b.y);
    o[2] = bf16_bits((v.z - mu) * rstd * g.z + b.z);
    o[3] = bf16_bits((v.w - mu) * rstd * g.w + b.w);
    *(u16x4*)(xn + (size_t)row * 1024 + t * 4) = o;
    return;
  }
  const float* in;
  __bf16* out;
  int R, C, bx, by;
  if (blk < 4096 + 768) {
    int i2 = blk - 4096;
    in = w_qkv; out = wqkvT; R = 1024; C = 3072;
    bx = i2 % 48; by = i2 / 48;
  } else {
    int i3 = blk - 4864;
    in = w_out; out = woutT; R = 1024; C = 1024;
    bx = i3 % 16; by = i3 / 16;
  }
  int tx = t & 15, ty = t >> 4;
  int c0 = bx * 64, r0 = by * 64;
#pragma unroll
  for (int p = 0; p < 4; ++p) {
    int r = ty + p * 16;
    float4 v = *(const float4*)(in + (size_t)(r0 + r) * C + c0 + tx * 4);
    tile[r][tx * 4 + 0] = v.x;
    tile[r][tx * 4 + 1] = v.y;
    tile[r][tx * 4 + 2] = v.z;
    tile[r][tx * 4 + 3] = v.w;
  }
  __syncthreads();
#pragma unroll
  for (int p = 0; p < 4; ++p) {
    int cc = ty + p * 16;
    u16x4 o;
    o[0] = bf16_bits(tile[tx * 4 + 0][cc]);
    o[1] = bf16_bits(tile[tx * 4 + 1][cc]);
    o[2] = bf16_bits(tile[tx * 4 + 2][cc]);
    o[3] = bf16_bits(tile[tx * 4 + 3][cc]);
    *(u16x4*)(out + (size_t)(c0 + cc) * R + r0 + tx * 4) = o;
  }
}

// ---------------------------------------------------------------- QKV GEMM
// r12/r17-verified: 128x128 tile, normal orientation, grid (24,32).
__global__ __launch_bounds__(256) void gemm_qkv_kernel(
    const __bf16* __restrict__ A, const __bf16* __restrict__ BT,
    __bf16* __restrict__ Qb, __bf16* __restrict__ Kb, __bf16* __restrict__ VTb) {
  __shared__ __align__(16) __bf16 Asm[128 * 32];
  __shared__ __align__(16) __bf16 Bsm[128 * 32];
  const int KD = 1024;
  int t = threadIdx.x;
  int w = t >> 6, ln = t & 63;
  int wr = w >> 1, wc = w & 1;
  int m0 = blockIdx.y * 128, n0 = blockIdx.x * 128;
  f32x4 acc[4][4] = {};

  int srow = w * 16 + (ln >> 2);
  int scol = (ln & 3) * 8;
  int lrow = ln & 15;
  int lkb = (ln >> 4) * 16;

  for (int kk = 0; kk < KD; kk += 32) {
    __syncthreads();
#pragma unroll
    for (int i = 0; i < 2; ++i) {
      int row = i * 64 + srow;
      gl_lds16(A + (size_t)(m0 + row) * KD + kk + scol,
               (char*)Asm + i * 4096 + w * 1024);
      gl_lds16(BT + (size_t)(n0 + row) * KD + kk + scol,
               (char*)Bsm + i * 4096 + w * 1024);
    }
    __syncthreads();
    bf16x8 af[4], bfr[4];
#pragma unroll
    for (int mi = 0; mi < 4; ++mi)
      af[mi] = *(const bf16x8*)((char*)Asm + (wr * 64 + mi * 16 + lrow) * 64 + lkb);
#pragma unroll
    for (int ni = 0; ni < 4; ++ni)
      bfr[ni] = *(const bf16x8*)((char*)Bsm + (wc * 64 + ni * 16 + lrow) * 64 + lkb);
#pragma unroll
    for (int mi = 0; mi < 4; ++mi)
#pragma unroll
      for (int ni = 0; ni < 4; ++ni)
        acc[mi][ni] = mfma16x16(af[mi], bfr[ni], acc[mi][ni]);
  }

  int r4 = (ln >> 4) * 4;
#pragma unroll
  for (int mi = 0; mi < 4; ++mi) {
#pragma unroll
    for (int ni = 0; ni < 4; ++ni) {
      int grow = m0 + wr * 64 + mi * 16 + r4;
      int gcol = n0 + wc * 64 + ni * 16 + lrow;
      int sel = gcol >> 10;
      int nl = gcol & 1023;
      int h = nl >> 6, d = nl & 63;
      int b = grow >> 11, seq = grow & 2047;
      int bh = b * 16 + h;
      if (sel < 2) {
        __bf16* dst = (sel == 0 ? Qb : Kb) + ((size_t)bh * 2048 + seq) * 64 + d;
#pragma unroll
        for (int r = 0; r < 4; ++r) dst[(size_t)r * 64] = (__bf16)acc[mi][ni][r];
      } else {
        u16x4 o;
        o[0] = bf16_bits(acc[mi][ni][0]);
        o[1] = bf16_bits(acc[mi][ni][1]);
        o[2] = bf16_bits(acc[mi][ni][2]);
        o[3] = bf16_bits(acc[mi][ni][3]);
        *(u16x4*)(VTb + ((size_t)bh * 64 + d) * 2048 + seq) = o;
      }
    }
  }
}

// ---------------------------------------------------------------- out GEMM
// r12/r17-verified: BM=128 x BN=64, normal orientation, grid (16,32).
__global__ __launch_bounds__(256) void gemm_out_kernel(
    const __bf16* __restrict__ A, const __bf16* __restrict__ BT,
    float* __restrict__ Cout, const float* __restrict__ bias) {
  __shared__ __align__(16) __bf16 Asm[128 * 32];  // 8KB
  __shared__ __align__(16) __bf16 Bsm[64 * 32];   // 4KB
  const int KD = 1024;
  int t = threadIdx.x;
  int w = t >> 6, ln = t & 63;
  int m0 = blockIdx.y * 128, n0 = blockIdx.x * 64;
  f32x4 acc[2][4] = {};

  int srow = w * 16 + (ln >> 2);  // 0..63
  int scol = (ln & 3) * 8;
  int lrow = ln & 15;
  int lkb = (ln >> 4) * 16;

  for (int kk = 0; kk < KD; kk += 32) {
    __syncthreads();
#pragma unroll
    for (int i = 0; i < 2; ++i)
      gl_lds16(A + (size_t)(m0 + i * 64 + srow) * KD + kk + scol,
               (char*)Asm + i * 4096 + w * 1024);
    gl_lds16(BT + (size_t)(n0 + srow) * KD + kk + scol, (char*)Bsm + w * 1024);
    __syncthreads();
    bf16x8 af[2], bfr[4];
#pragma unroll
    for (int mi = 0; mi < 2; ++mi)
      af[mi] = *(const bf16x8*)((char*)Asm + (w * 32 + mi * 16 + lrow) * 64 + lkb);
#pragma unroll
    for (int ni = 0; ni < 4; ++ni)
      bfr[ni] = *(const bf16x8*)((char*)Bsm + (ni * 16 + lrow) * 64 + lkb);
#pragma unroll
    for (int mi = 0; mi < 2; ++mi)
#pragma unroll
      for (int ni = 0; ni < 4; ++ni)
        acc[mi][ni] = mfma16x16(af[mi], bfr[ni], acc[mi][ni]);
  }

  int r4 = (ln >> 4) * 4;
#pragma unroll
  for (int mi = 0; mi < 2; ++mi) {
#pragma unroll
    for (int ni = 0; ni < 4; ++ni) {
      int grow = m0 + w * 32 + mi * 16 + r4;
      int gcol = n0 + ni * 16 + lrow;
      float bv = bias[gcol];
#pragma unroll
      for (int r = 0; r < 4; ++r)
        Cout[(size_t)(grow + r) * 1024 + gcol] = acc[mi][ni][r] + bv;
    }
  }
}

// ---------------------------------------------------------------- attention
// r11/r12/r17-verified j-SPLIT flash + Round-18 change: V fragments loaded
// DIRECTLY from global into registers (T14 issue-early/consume-late): the 8
// independent 16B loads issue at loop top and are covered by QK^T + softmax
// (~400+ cyc) before PV consumes them — unlike r9's unshielded version.
// K stays LDS-staged (feeds QK immediately; 4x inter-wave reuse). Effects:
// STAGE halves, V's LDS bank conflicts disappear, Vlds freed.
__global__ __launch_bounds__(256, 2) void attn_kernel(
    const __bf16* __restrict__ Qb, const __bf16* __restrict__ Kb,
    const __bf16* __restrict__ VTb, __bf16* __restrict__ Opart,
    float* __restrict__ lbuf) {
  __shared__ __align__(16) char Klds[16384];   // 2 bufs x [64 j][128B], swizzled
  const float LOG2E = 1.44269504f;
  const float K1 = 0.125f * LOG2E;
  int t = threadIdx.x, w = t >> 6, ln = t & 63;
  int hi = ln >> 5, col = ln & 31;
  int bh = blockIdx.y, bq = bh >> 4, h = bh & 15;
  int q0 = blockIdx.x * 128;
  int jh = blockIdx.z;                 // j-half: tiles jh*16 .. jh*16+15
  const __bf16* Qh = Qb + (size_t)bh * 2048 * 64;
  const __bf16* Kh = Kb + (size_t)bh * 2048 * 64;
  const __bf16* Vh = VTb + (size_t)bh * 64 * 2048;
  __bf16* Oh = Opart + (size_t)jh * 4096 * 1024;  // half = 4M bf16 = 8MB

  bf16x8 qf[4];
  int qrow = q0 + w * 32 + col;
#pragma unroll
  for (int dk = 0; dk < 4; ++dk)
    qf[dk] = *(const bf16x8*)(Qh + (size_t)qrow * 64 + dk * 16 + hi * 8);

  f32x16 oacc0 = {}, oacc1 = {};
  float l_run = 0.f;

  // V direct-load bases: vreg0[jk] = V^T[d=col][j0 + jk*16 + hi*8 ..+7]
  const __bf16* Vr0 = Vh + (size_t)col * 2048 + hi * 8;
  const __bf16* Vr1 = Vh + (size_t)(32 + col) * 2048 + hi * 8;

  int sj0 = t >> 3, sc0 = (t & 7) ^ (sj0 & 7);
  int sj1 = 32 + (t >> 3), sc1 = (t & 7) ^ (sj1 & 7);

#define STAGE(off, j0_)                                                        \
  do {                                                                         \
    gl_lds16(Kh + (size_t)((j0_) + sj0) * 64 + sc0 * 8, Klds + (off) + w * 1024); \
    gl_lds16(Kh + (size_t)((j0_) + sj1) * 64 + sc1 * 8,                        \
             Klds + (off) + 4096 + w * 1024);                                  \
  } while (0)

  int jbase = jh * 16;
  int cur = 0;
  STAGE(0, jbase * 64);
  WAITVM0;
  __builtin_amdgcn_s_barrier();
  __builtin_amdgcn_sched_barrier(0);

  for (int jt = 0; jt < 16; ++jt) {
    int j0 = (jbase + jt) * 64;
    // T14: issue current tile's V loads FIRST — consumed by PV after
    // QK^T + softmax (~400+ cycles of cover).
    bf16x8 vreg0[4], vreg1[4];
#pragma unroll
    for (int jk = 0; jk < 4; ++jk) {
      vreg0[jk] = *(const bf16x8*)(Vr0 + j0 + jk * 16);
      vreg1[jk] = *(const bf16x8*)(Vr1 + j0 + jk * 16);
    }
    if (jt < 15) STAGE((cur ^ 1) * 8192, j0 + 64);
    const char* Kc = Klds + cur * 8192;

    // QK^T: sfr[s] = S^T[j = 32s + crow(r,hi)][i = col]
    f32x16 sfr0 = {}, sfr1 = {};
#pragma unroll
    for (int dk = 0; dk < 4; ++dk) {
      int sw = ((dk * 32 + hi * 16) ^ ((col & 7) << 4));
      bf16x8 kf0 = *(const bf16x8*)(Kc + col * 128 + sw);
      bf16x8 kf1 = *(const bf16x8*)(Kc + (32 + col) * 128 + sw);
      sfr0 = mfma32(kf0, qf[dk], sfr0);
      sfr1 = mfma32(kf1, qf[dk], sfr1);
    }

    // no-max softmax: p = exp2(S*K1); pack to bf16 PV B-frags (T12).
    float psum = 0.f;
    bf16x8 pfr[4];
#pragma unroll
    for (int jk = 0; jk < 4; ++jk) {
      float p[8];
#pragma unroll
      for (int c = 0; c < 8; ++c) {
        float sv = (jk < 2) ? sfr0[(jk & 1) * 8 + c] : sfr1[(jk & 1) * 8 + c];
        p[c] = __builtin_amdgcn_exp2f(sv * K1);
      }
      psum += ((p[0] + p[1]) + (p[2] + p[3])) + ((p[4] + p[5]) + (p[6] + p[7]));
      unsigned X0 = cvtpk_bf16(p[0], p[1]);
      unsigned X1 = cvtpk_bf16(p[2], p[3]);
      unsigned Y0 = cvtpk_bf16(p[4], p[5]);
      unsigned Y1 = cvtpk_bf16(p[6], p[7]);
      pl32swap(X0, Y0);
      pl32swap(X1, Y1);
      union { unsigned u[4]; bf16x8 v; } pu;
      pu.u[0] = X0; pu.u[1] = X1; pu.u[2] = Y0; pu.u[3] = Y1;
      pfr[jk] = pu.v;
    }
    l_run += psum;

    // PV: O^T[d][i] += V^T[d][j] P^T[j][i] — V from registers.
#pragma unroll
    for (int jk = 0; jk < 4; ++jk) {
      oacc0 = mfma32(vreg0[jk], pfr[jk], oacc0);
      oacc1 = mfma32(vreg1[jk], pfr[jk], oacc1);
    }

    WAITVM0;
    __builtin_amdgcn_s_barrier();
    __builtin_amdgcn_sched_barrier(0);
    cur ^= 1;
  }
#undef STAGE

  l_run += __shfl_xor(l_run, 32);
  float linv = 1.0f / l_run;
  if (hi == 0)
    lbuf[(((size_t)bh * 16 + blockIdx.x) * 2 + jh) * 128 + w * 32 + col] = l_run;

  // epilogue: normalize, transpose O^T -> O via per-wave LDS (exclusive
  // 4KB regions of Klds), coalesced 16B stores.
  char* Ow = Klds + w * 4096;  // [32 i][128B d-row], swizzled
#pragma unroll
  for (int da = 0; da < 2; ++da) {
    const f32x16& oa = da ? oacc1 : oacc0;
#pragma unroll
    for (int g = 0; g < 4; ++g) {
      unsigned w0 = cvtpk_bf16(oa[g * 4 + 0] * linv, oa[g * 4 + 1] * linv);
      unsigned w1 = cvtpk_bf16(oa[g * 4 + 2] * linv, oa[g * 4 + 3] * linv);
      int dby = da * 64 + g * 16 + hi * 8;
      char* dst = Ow + col * 128 + ((dby & ~15) ^ ((col & 7) << 4)) + (dby & 8);
      u32x2 pr = {w0, w1};
      *(u32x2*)dst = pr;
    }
  }
  int rr0 = ln >> 3, c16o = ln & 7;
#pragma unroll
  for (int pp = 0; pp < 4; ++pp) {
    int rr = rr0 + pp * 8;
    bf16x8 ov = *(const bf16x8*)(Ow + rr * 128 + ((c16o * 16) ^ ((rr & 7) << 4)));
    int grow = bq * 2048 + q0 + w * 32 + rr;
    *(bf16x8*)(Oh + (size_t)grow * 1024 + h * 64 + c16o * 8) = ov;
  }
}

// ------------------------------------------------------------- combine
// vectorized — 8 elems (16B)/thread, grid 2048x256 (r12/r17-verified).
__global__ __launch_bounds__(256) void combine_kernel(
    __bf16* __restrict__ O0, const __bf16* __restrict__ O1,
    const float* __restrict__ lbuf) {
  int idx = blockIdx.x * 256 + threadIdx.x;
  int e0 = idx * 8;
  int r = e0 >> 10, c0 = e0 & 1023;
  int b = r >> 11, seq = r & 2047, qb = seq >> 7, i = seq & 127;
  int h = c0 >> 6;
  int bh = b * 16 + h;
  size_t lbase = (((size_t)bh * 16 + qb) * 2) * 128 + i;
  float l0 = lbuf[lbase], l1 = lbuf[lbase + 128];
  float inv = 1.0f / (l0 + l1);
  float w0 = l0 * inv, w1 = l1 * inv;
  bf16x8 a = *(const bf16x8*)(O0 + e0);
  bf16x8 bb = *(const bf16x8*)(O1 + e0);
  unsigned u[4];
#pragma unroll
  for (int j = 0; j < 4; ++j) {
    float lo = w0 * bf16_f32(a[2 * j]) + w1 * bf16_f32(bb[2 * j]);
    float hi2 = w0 * bf16_f32(a[2 * j + 1]) + w1 * bf16_f32(bb[2 * j + 1]);
    u[j] = cvtpk_bf16(lo, hi2);
  }
  union { unsigned uu[4]; bf16x8 v; } pu;
  pu.uu[0] = u[0]; pu.uu[1] = u[1]; pu.uu[2] = u[2]; pu.uu[3] = u[3];
  *(bf16x8*)(O0 + e0) = pu.v;
}

// ---------------------------------------------------------------- launch
extern "C" void kernel_launch(void* const* d_in, const int* in_sizes, int n_in,
                              void* d_out, int out_size, void* d_ws, size_t ws_size,
                              hipStream_t stream) {
  const float* x = (const float*)d_in[0];
  const float* gamma = (const float*)d_in[1];
  const float* beta = (const float*)d_in[2];
  const float* w_qkv = (const float*)d_in[3];
  const float* w_out = (const float*)d_in[4];
  const float* b_out = (const float*)d_in[5];

  char* ws = (char*)d_ws;
  // [0..8): xn / attn half-0 partial / final sa (in-place combine)
  // [8..16): attn half-1 partial
  // [16..22): wqkvT (dead after QKV GEMM; first 1MB reused as lbuf by attn)
  // [22..24): woutT
  // [24..32): Qb   [32..40): Kb   [40..48): VTb
  __bf16* xn = (__bf16*)(ws);
  __bf16* Opart = xn;                               // halves at +0MB / +8MB
  float* lbuf = (float*)(ws + (16l << 20));
  __bf16* wqkvT = (__bf16*)(ws + (16l << 20));
  __bf16* woutT = (__bf16*)(ws + (22l << 20));
  __bf16* Qb = (__bf16*)(ws + (24l << 20));
  __bf16* Kb = (__bf16*)(ws + (32l << 20));
  __bf16* VTb = (__bf16*)(ws + (40l << 20));
  __bf16* sa = xn;  // combine merges half-1 into half-0 in place

  prep_kernel<<<5120, 256, 0, stream>>>(x, gamma, beta, xn, w_qkv, wqkvT,
                                        w_out, woutT);
  gemm_qkv_kernel<<<dim3(24, 32), 256, 0, stream>>>(xn, wqkvT, Qb, Kb, VTb);
  attn_kernel<<<dim3(16, 32, 2), 256, 0, stream>>>(Qb, Kb, VTb, Opart, lbuf);
  combine_kernel<<<2048, 256, 0, stream>>>(sa, Opart + (4096l * 1024), lbuf);
  gemm_out_kernel<<<dim3(16, 32), 256, 0, stream>>>(sa, woutT, (float*)d_out, b_out);
}

// Round 19
// 138.459 us; speedup vs baseline: 1.0883x; 1.0883x over previous
//
#include <hip/hip_runtime.h>

typedef __attribute__((ext_vector_type(4))) float f32x4;
typedef __attribute__((ext_vector_type(16))) float f32x16;
typedef __attribute__((ext_vector_type(8))) __bf16 bf16x8;
typedef __attribute__((ext_vector_type(4))) unsigned short u16x4;
typedef __attribute__((ext_vector_type(2))) unsigned int u32x2;

#define DEVI static __device__ __forceinline__

DEVI unsigned short bf16_bits(float f) {
  __bf16 h = (__bf16)f;
  return __builtin_bit_cast(unsigned short, h);
}

DEVI float bf16_f32(__bf16 u) { return (float)u; }

DEVI void gl_lds16(const void* g, void* l) {
  __builtin_amdgcn_global_load_lds(
      (const __attribute__((address_space(1))) void*)g,
      (__attribute__((address_space(3))) void*)l, 16, 0, 0);
}

DEVI f32x4 mfma16x16(bf16x8 a, bf16x8 b, f32x4 c) {
  return __builtin_amdgcn_mfma_f32_16x16x32_bf16(a, b, c, 0, 0, 0);
}

DEVI f32x16 mfma32(bf16x8 a, bf16x8 b, f32x16 c) {
  return __builtin_amdgcn_mfma_f32_32x32x16_bf16(a, b, c, 0, 0, 0);
}

DEVI unsigned cvtpk_bf16(float lo, float hi2) {
  unsigned r;
  asm("v_cvt_pk_bf16_f32 %0, %1, %2" : "=v"(r) : "v"(lo), "v"(hi2));
  return r;
}

// NOTE (r3/r4): never call with two copies of one value (allocator coalesces).
// NOTE (r15/r16): MFMA whose ONLY inputs are INLINEASM-built fragments gave
// schedule-dependent wrong results — abandoned.
// NOTE (r18): per-lane direct global fragment loads (row-per-lane) are
// uncoalesced (64 lines/instr) — staging via gl_lds is the coalescer; LDS
// conflicts there are the price of the transpose, not removable waste.
DEVI void pl32swap(unsigned& a, unsigned& b) {
  asm volatile("s_nop 1\nv_permlane32_swap_b32 %0, %1\ns_nop 1"
               : "+v"(a), "+v"(b));
}

#define WAITVM0 asm volatile("s_waitcnt vmcnt(0)" ::: "memory")

// ---------------------------------------------------------------- prep
// Fused ln (blocks 0..4095) + w_qkv transpose (4096..4863) + w_out
// transpose (4864..5119). r13/r14/r17-verified.
__global__ __launch_bounds__(256) void prep_kernel(
    const float* __restrict__ x, const float* __restrict__ gamma,
    const float* __restrict__ beta, __bf16* __restrict__ xn,
    const float* __restrict__ w_qkv, __bf16* __restrict__ wqkvT,
    const float* __restrict__ w_out, __bf16* __restrict__ woutT) {
  __shared__ float tile[64][65];
  __shared__ float red[8];
  int blk = blockIdx.x;
  int t = threadIdx.x;
  if (blk < 4096) {
    int row = blk;
    float4 v = ((const float4*)(x + (size_t)row * 1024))[t];
    float s = v.x + v.y + v.z + v.w;
    float sq = v.x * v.x + v.y * v.y + v.z * v.z + v.w * v.w;
#pragma unroll
    for (int off = 32; off > 0; off >>= 1) {
      s += __shfl_down(s, off);
      sq += __shfl_down(sq, off);
    }
    int w = t >> 6, ln = t & 63;
    if (ln == 0) { red[w] = s; red[4 + w] = sq; }
    __syncthreads();
    s = red[0] + red[1] + red[2] + red[3];
    sq = red[4] + red[5] + red[6] + red[7];
    float mu = s * (1.0f / 1024.0f);
    float var = sq * (1.0f / 1024.0f) - mu * mu;
    float rstd = rsqrtf(var + 1e-5f);
    float4 g = ((const float4*)gamma)[t];
    float4 b = ((const float4*)beta)[t];
    u16x4 o;
    o[0] = bf16_bits((v.x - mu) * rstd * g.x + b.x);
    o[1] = bf16_bits((v.y - mu) * rstd * g.y + b.y);
    o[2] = bf16_bits((v.z - mu) * rstd * g.z + b.z);
    o[3] = bf16_bits((v.w - mu) * rstd * g.w + b.w);
    *(u16x4*)(xn + (size_t)row * 1024 + t * 4) = o;
    return;
  }
  const float* in;
  __bf16* out;
  int R, C, bx, by;
  if (blk < 4096 + 768) {
    int i2 = blk - 4096;
    in = w_qkv; out = wqkvT; R = 1024; C = 3072;
    bx = i2 % 48; by = i2 / 48;
  } else {
    int i3 = blk - 4864;
    in = w_out; out = woutT; R = 1024; C = 1024;
    bx = i3 % 16; by = i3 / 16;
  }
  int tx = t & 15, ty = t >> 4;
  int c0 = bx * 64, r0 = by * 64;
#pragma unroll
  for (int p = 0; p < 4; ++p) {
    int r = ty + p * 16;
    float4 v = *(const float4*)(in + (size_t)(r0 + r) * C + c0 + tx * 4);
    tile[r][tx * 4 + 0] = v.x;
    tile[r][tx * 4 + 1] = v.y;
    tile[r][tx * 4 + 2] = v.z;
    tile[r][tx * 4 + 3] = v.w;
  }
  __syncthreads();
#pragma unroll
  for (int p = 0; p < 4; ++p) {
    int cc = ty + p * 16;
    u16x4 o;
    o[0] = bf16_bits(tile[tx * 4 + 0][cc]);
    o[1] = bf16_bits(tile[tx * 4 + 1][cc]);
    o[2] = bf16_bits(tile[tx * 4 + 2][cc]);
    o[3] = bf16_bits(tile[tx * 4 + 3][cc]);
    *(u16x4*)(out + (size_t)(c0 + cc) * R + r0 + tx * 4) = o;
  }
}

// ---------------------------------------------------------------- QKV GEMM
// r12/r17-verified: 128x128 tile, normal orientation, grid (24,32).
__global__ __launch_bounds__(256) void gemm_qkv_kernel(
    const __bf16* __restrict__ A, const __bf16* __restrict__ BT,
    __bf16* __restrict__ Qb, __bf16* __restrict__ Kb, __bf16* __restrict__ VTb) {
  __shared__ __align__(16) __bf16 Asm[128 * 32];
  __shared__ __align__(16) __bf16 Bsm[128 * 32];
  const int KD = 1024;
  int t = threadIdx.x;
  int w = t >> 6, ln = t & 63;
  int wr = w >> 1, wc = w & 1;
  int m0 = blockIdx.y * 128, n0 = blockIdx.x * 128;
  f32x4 acc[4][4] = {};

  int srow = w * 16 + (ln >> 2);
  int scol = (ln & 3) * 8;
  int lrow = ln & 15;
  int lkb = (ln >> 4) * 16;

  for (int kk = 0; kk < KD; kk += 32) {
    __syncthreads();
#pragma unroll
    for (int i = 0; i < 2; ++i) {
      int row = i * 64 + srow;
      gl_lds16(A + (size_t)(m0 + row) * KD + kk + scol,
               (char*)Asm + i * 4096 + w * 1024);
      gl_lds16(BT + (size_t)(n0 + row) * KD + kk + scol,
               (char*)Bsm + i * 4096 + w * 1024);
    }
    __syncthreads();
    bf16x8 af[4], bfr[4];
#pragma unroll
    for (int mi = 0; mi < 4; ++mi)
      af[mi] = *(const bf16x8*)((char*)Asm + (wr * 64 + mi * 16 + lrow) * 64 + lkb);
#pragma unroll
    for (int ni = 0; ni < 4; ++ni)
      bfr[ni] = *(const bf16x8*)((char*)Bsm + (wc * 64 + ni * 16 + lrow) * 64 + lkb);
#pragma unroll
    for (int mi = 0; mi < 4; ++mi)
#pragma unroll
      for (int ni = 0; ni < 4; ++ni)
        acc[mi][ni] = mfma16x16(af[mi], bfr[ni], acc[mi][ni]);
  }

  int r4 = (ln >> 4) * 4;
#pragma unroll
  for (int mi = 0; mi < 4; ++mi) {
#pragma unroll
    for (int ni = 0; ni < 4; ++ni) {
      int grow = m0 + wr * 64 + mi * 16 + r4;
      int gcol = n0 + wc * 64 + ni * 16 + lrow;
      int sel = gcol >> 10;
      int nl = gcol & 1023;
      int h = nl >> 6, d = nl & 63;
      int b = grow >> 11, seq = grow & 2047;
      int bh = b * 16 + h;
      if (sel < 2) {
        __bf16* dst = (sel == 0 ? Qb : Kb) + ((size_t)bh * 2048 + seq) * 64 + d;
#pragma unroll
        for (int r = 0; r < 4; ++r) dst[(size_t)r * 64] = (__bf16)acc[mi][ni][r];
      } else {
        u16x4 o;
        o[0] = bf16_bits(acc[mi][ni][0]);
        o[1] = bf16_bits(acc[mi][ni][1]);
        o[2] = bf16_bits(acc[mi][ni][2]);
        o[3] = bf16_bits(acc[mi][ni][3]);
        *(u16x4*)(VTb + ((size_t)bh * 64 + d) * 2048 + seq) = o;
      }
    }
  }
}

// ---------------------------------------------------------------- out GEMM
// Round-19: combine FUSED into A-staging. A = w0*O0 + w1*O1 (row+head
// weights from lbuf), reg-staged: coalesced 16B loads from O0/O1, f32
// combine, cvt_pk to bf16, ds_write to the SAME LDS slot gl_lds used
// (base + lane*16). head h = kk>>6 is thread-uniform (scol<=24<64);
// lbuf index = b*65536 + qb*256 + ii + h*4096 (+128 for l1).
__global__ __launch_bounds__(256) void gemm_out_kernel(
    const __bf16* __restrict__ O0, const __bf16* __restrict__ O1,
    const float* __restrict__ lbuf, const __bf16* __restrict__ BT,
    float* __restrict__ Cout, const float* __restrict__ bias) {
  __shared__ __align__(16) __bf16 Asm[128 * 32];  // 8KB
  __shared__ __align__(16) __bf16 Bsm[64 * 32];   // 4KB
  const int KD = 1024;
  int t = threadIdx.x;
  int w = t >> 6, ln = t & 63;
  int m0 = blockIdx.y * 128, n0 = blockIdx.x * 64;
  f32x4 acc[2][4] = {};

  int srow = w * 16 + (ln >> 2);  // 0..63
  int scol = (ln & 3) * 8;
  int lrow = ln & 15;
  int lkb = (ln >> 4) * 16;

  // per-issue row constants for the combine weights
  int rowg[2], lconst[2];
#pragma unroll
  for (int i = 0; i < 2; ++i) {
    rowg[i] = m0 + i * 64 + srow;
    int b = rowg[i] >> 11, seq = rowg[i] & 2047;
    int qb = seq >> 7, ii = seq & 127;
    lconst[i] = b * 65536 + qb * 256 + ii;
  }
  float w0[2], w1[2];

  for (int kk = 0; kk < KD; kk += 32) {
    __syncthreads();
    if ((kk & 63) == 0) {  // head changes every 64 cols (wave-uniform)
      int h = kk >> 6;
#pragma unroll
      for (int i = 0; i < 2; ++i) {
        float l0 = lbuf[lconst[i] + h * 4096];
        float l1 = lbuf[lconst[i] + h * 4096 + 128];
        float inv = 1.0f / (l0 + l1);
        w0[i] = l0 * inv;
        w1[i] = l1 * inv;
      }
    }
    // A-stage: combined O halves -> bf16 -> LDS (slot = base + lane*16)
#pragma unroll
    for (int i = 0; i < 2; ++i) {
      bf16x8 a8 = *(const bf16x8*)(O0 + (size_t)rowg[i] * 1024 + kk + scol);
      bf16x8 b8 = *(const bf16x8*)(O1 + (size_t)rowg[i] * 1024 + kk + scol);
      unsigned u[4];
#pragma unroll
      for (int j = 0; j < 4; ++j) {
        float lo = w0[i] * bf16_f32(a8[2 * j]) + w1[i] * bf16_f32(b8[2 * j]);
        float hi2 =
            w0[i] * bf16_f32(a8[2 * j + 1]) + w1[i] * bf16_f32(b8[2 * j + 1]);
        u[j] = cvtpk_bf16(lo, hi2);
      }
      union { unsigned uu[4]; bf16x8 v; } pu;
      pu.uu[0] = u[0]; pu.uu[1] = u[1]; pu.uu[2] = u[2]; pu.uu[3] = u[3];
      *(bf16x8*)((char*)Asm + i * 4096 + w * 1024 + ln * 16) = pu.v;
    }
    gl_lds16(BT + (size_t)(n0 + srow) * KD + kk + scol, (char*)Bsm + w * 1024);
    __syncthreads();
    bf16x8 af[2], bfr[4];
#pragma unroll
    for (int mi = 0; mi < 2; ++mi)
      af[mi] = *(const bf16x8*)((char*)Asm + (w * 32 + mi * 16 + lrow) * 64 + lkb);
#pragma unroll
    for (int ni = 0; ni < 4; ++ni)
      bfr[ni] = *(const bf16x8*)((char*)Bsm + (ni * 16 + lrow) * 64 + lkb);
#pragma unroll
    for (int mi = 0; mi < 2; ++mi)
#pragma unroll
      for (int ni = 0; ni < 4; ++ni)
        acc[mi][ni] = mfma16x16(af[mi], bfr[ni], acc[mi][ni]);
  }

  int r4 = (ln >> 4) * 4;
#pragma unroll
  for (int mi = 0; mi < 2; ++mi) {
#pragma unroll
    for (int ni = 0; ni < 4; ++ni) {
      int grow = m0 + w * 32 + mi * 16 + r4;
      int gcol = n0 + ni * 16 + lrow;
      float bv = bias[gcol];
#pragma unroll
      for (int r = 0; r < 4; ++r)
        Cout[(size_t)(grow + r) * 1024 + gcol] = acc[mi][ni][r] + bv;
    }
  }
}

// ---------------------------------------------------------------- attention
// r11/r12/r17-verified: j-SPLIT flash (exact under no-max softmax),
// grid (16,32,2). Byte-identical to r17.
__global__ __launch_bounds__(256, 2) void attn_kernel(
    const __bf16* __restrict__ Qb, const __bf16* __restrict__ Kb,
    const __bf16* __restrict__ VTb, __bf16* __restrict__ Opart,
    float* __restrict__ lbuf) {
  __shared__ __align__(16) char Klds[16384];   // 2 bufs x [64 j][128B], swizzled
  __shared__ __align__(16) char Vlds[16384];   // 2 bufs x [64 d][128B], swizzled
  const float LOG2E = 1.44269504f;
  const float K1 = 0.125f * LOG2E;
  int t = threadIdx.x, w = t >> 6, ln = t & 63;
  int hi = ln >> 5, col = ln & 31;
  int bh = blockIdx.y, bq = bh >> 4, h = bh & 15;
  int q0 = blockIdx.x * 128;
  int jh = blockIdx.z;                 // j-half: tiles jh*16 .. jh*16+15
  const __bf16* Qh = Qb + (size_t)bh * 2048 * 64;
  const __bf16* Kh = Kb + (size_t)bh * 2048 * 64;
  const __bf16* Vh = VTb + (size_t)bh * 64 * 2048;
  __bf16* Oh = Opart + (size_t)jh * 4096 * 1024;  // half = 4M bf16 = 8MB

  bf16x8 qf[4];
  int qrow = q0 + w * 32 + col;
#pragma unroll
  for (int dk = 0; dk < 4; ++dk)
    qf[dk] = *(const bf16x8*)(Qh + (size_t)qrow * 64 + dk * 16 + hi * 8);

  f32x16 oacc0 = {}, oacc1 = {};
  float l_run = 0.f;

  int sj0 = t >> 3, sc0 = (t & 7) ^ (sj0 & 7);
  int sj1 = 32 + (t >> 3), sc1 = (t & 7) ^ (sj1 & 7);

#define STAGE(off, j0_)                                                        \
  do {                                                                         \
    gl_lds16(Kh + (size_t)((j0_) + sj0) * 64 + sc0 * 8, Klds + (off) + w * 1024); \
    gl_lds16(Kh + (size_t)((j0_) + sj1) * 64 + sc1 * 8,                        \
             Klds + (off) + 4096 + w * 1024);                                  \
    gl_lds16(Vh + (size_t)sj0 * 2048 + (j0_) + sc0 * 8, Vlds + (off) + w * 1024); \
    gl_lds16(Vh + (size_t)sj1 * 2048 + (j0_) + sc1 * 8,                        \
             Vlds + (off) + 4096 + w * 1024);                                  \
  } while (0)

  int jbase = jh * 16;
  int cur = 0;
  STAGE(0, jbase * 64);
  WAITVM0;
  __builtin_amdgcn_s_barrier();
  __builtin_amdgcn_sched_barrier(0);

  for (int jt = 0; jt < 16; ++jt) {
    if (jt < 15) STAGE((cur ^ 1) * 8192, (jbase + jt + 1) * 64);
    const char* Kc = Klds + cur * 8192;
    const char* Vc = Vlds + cur * 8192;

    f32x16 sfr0 = {}, sfr1 = {};
#pragma unroll
    for (int dk = 0; dk < 4; ++dk) {
      int sw = ((dk * 32 + hi * 16) ^ ((col & 7) << 4));
      bf16x8 kf0 = *(const bf16x8*)(Kc + col * 128 + sw);
      bf16x8 kf1 = *(const bf16x8*)(Kc + (32 + col) * 128 + sw);
      sfr0 = mfma32(kf0, qf[dk], sfr0);
      sfr1 = mfma32(kf1, qf[dk], sfr1);
    }

    float psum = 0.f;
    bf16x8 pfr[4];
#pragma unroll
    for (int jk = 0; jk < 4; ++jk) {
      float p[8];
#pragma unroll
      for (int c = 0; c < 8; ++c) {
        float sv = (jk < 2) ? sfr0[(jk & 1) * 8 + c] : sfr1[(jk & 1) * 8 + c];
        p[c] = __builtin_amdgcn_exp2f(sv * K1);
      }
      psum += ((p[0] + p[1]) + (p[2] + p[3])) + ((p[4] + p[5]) + (p[6] + p[7]));
      unsigned X0 = cvtpk_bf16(p[0], p[1]);
      unsigned X1 = cvtpk_bf16(p[2], p[3]);
      unsigned Y0 = cvtpk_bf16(p[4], p[5]);
      unsigned Y1 = cvtpk_bf16(p[6], p[7]);
      pl32swap(X0, Y0);
      pl32swap(X1, Y1);
      union { unsigned u[4]; bf16x8 v; } pu;
      pu.u[0] = X0; pu.u[1] = X1; pu.u[2] = Y0; pu.u[3] = Y1;
      pfr[jk] = pu.v;
    }
    l_run += psum;

#pragma unroll
    for (int jk = 0; jk < 4; ++jk) {
      int sw = ((jk * 32 + hi * 16) ^ ((col & 7) << 4));
      bf16x8 vf0 = *(const bf16x8*)(Vc + col * 128 + sw);
      bf16x8 vf1 = *(const bf16x8*)(Vc + (32 + col) * 128 + sw);
      oacc0 = mfma32(vf0, pfr[jk], oacc0);
      oacc1 = mfma32(vf1, pfr[jk], oacc1);
    }

    WAITVM0;
    __builtin_amdgcn_s_barrier();
    __builtin_amdgcn_sched_barrier(0);
    cur ^= 1;
  }
#undef STAGE

  l_run += __shfl_xor(l_run, 32);
  float linv = 1.0f / l_run;
  if (hi == 0)
    lbuf[(((size_t)bh * 16 + blockIdx.x) * 2 + jh) * 128 + w * 32 + col] = l_run;

  char* Ow = Klds + w * 4096;  // [32 i][128B d-row], swizzled
#pragma unroll
  for (int da = 0; da < 2; ++da) {
    const f32x16& oa = da ? oacc1 : oacc0;
#pragma unroll
    for (int g = 0; g < 4; ++g) {
      unsigned w0 = cvtpk_bf16(oa[g * 4 + 0] * linv, oa[g * 4 + 1] * linv);
      unsigned w1 = cvtpk_bf16(oa[g * 4 + 2] * linv, oa[g * 4 + 3] * linv);
      int dby = da * 64 + g * 16 + hi * 8;
      char* dst = Ow + col * 128 + ((dby & ~15) ^ ((col & 7) << 4)) + (dby & 8);
      u32x2 pr = {w0, w1};
      *(u32x2*)dst = pr;
    }
  }
  int rr0 = ln >> 3, c16o = ln & 7;
#pragma unroll
  for (int pp = 0; pp < 4; ++pp) {
    int rr = rr0 + pp * 8;
    bf16x8 ov = *(const bf16x8*)(Ow + rr * 128 + ((c16o * 16) ^ ((rr & 7) << 4)));
    int grow = bq * 2048 + q0 + w * 32 + rr;
    *(bf16x8*)(Oh + (size_t)grow * 1024 + h * 64 + c16o * 8) = ov;
  }
}

// ---------------------------------------------------------------- launch
extern "C" void kernel_launch(void* const* d_in, const int* in_sizes, int n_in,
                              void* d_out, int out_size, void* d_ws, size_t ws_size,
                              hipStream_t stream) {
  const float* x = (const float*)d_in[0];
  const float* gamma = (const float*)d_in[1];
  const float* beta = (const float*)d_in[2];
  const float* w_qkv = (const float*)d_in[3];
  const float* w_out = (const float*)d_in[4];
  const float* b_out = (const float*)d_in[5];

  char* ws = (char*)d_ws;
  // [0..8): xn / attn half-0 partial (O0)
  // [8..16): attn half-1 partial (O1)
  // [16..22): wqkvT (dead after QKV GEMM; first 1MB reused as lbuf by attn)
  // [22..24): woutT
  // [24..32): Qb   [32..40): Kb   [40..48): VTb
  __bf16* xn = (__bf16*)(ws);
  __bf16* Opart = xn;                               // halves at +0MB / +8MB
  float* lbuf = (float*)(ws + (16l << 20));
  __bf16* wqkvT = (__bf16*)(ws + (16l << 20));
  __bf16* woutT = (__bf16*)(ws + (22l << 20));
  __bf16* Qb = (__bf16*)(ws + (24l << 20));
  __bf16* Kb = (__bf16*)(ws + (32l << 20));
  __bf16* VTb = (__bf16*)(ws + (40l << 20));

  prep_kernel<<<5120, 256, 0, stream>>>(x, gamma, beta, xn, w_qkv, wqkvT,
                                        w_out, woutT);
  gemm_qkv_kernel<<<dim3(24, 32), 256, 0, stream>>>(xn, wqkvT, Qb, Kb, VTb);
  attn_kernel<<<dim3(16, 32, 2), 256, 0, stream>>>(Qb, Kb, VTb, Opart, lbuf);
  gemm_out_kernel<<<dim3(16, 32), 256, 0, stream>>>(
      Opart, Opart + (4096l * 1024), lbuf, woutT, (float*)d_out, b_out);
}

// Round 20
// 120.834 us; speedup vs baseline: 1.2471x; 1.1459x over previous
//
#include <hip/hip_runtime.h>

typedef __attribute__((ext_vector_type(4))) float f32x4;
typedef __attribute__((ext_vector_type(16))) float f32x16;
typedef __attribute__((ext_vector_type(8))) __bf16 bf16x8;
typedef __attribute__((ext_vector_type(4))) unsigned short u16x4;
typedef __attribute__((ext_vector_type(2))) unsigned int u32x2;

#define DEVI static __device__ __forceinline__

DEVI unsigned short bf16_bits(float f) {
  __bf16 h = (__bf16)f;
  return __builtin_bit_cast(unsigned short, h);
}

DEVI float bf16_f32(__bf16 u) { return (float)u; }

DEVI void gl_lds16(const void* g, void* l) {
  __builtin_amdgcn_global_load_lds(
      (const __attribute__((address_space(1))) void*)g,
      (__attribute__((address_space(3))) void*)l, 16, 0, 0);
}

DEVI f32x4 mfma16x16(bf16x8 a, bf16x8 b, f32x4 c) {
  return __builtin_amdgcn_mfma_f32_16x16x32_bf16(a, b, c, 0, 0, 0);
}

DEVI f32x16 mfma32(bf16x8 a, bf16x8 b, f32x16 c) {
  return __builtin_amdgcn_mfma_f32_32x32x16_bf16(a, b, c, 0, 0, 0);
}

DEVI unsigned cvtpk_bf16(float lo, float hi2) {
  unsigned r;
  asm("v_cvt_pk_bf16_f32 %0, %1, %2" : "=v"(r) : "v"(lo), "v"(hi2));
  return r;
}

// NOTE (r3/r4): never call with two copies of one value (allocator coalesces).
// NOTE (r15/r16): MFMA whose ONLY inputs are INLINEASM-built fragments gave
// schedule-dependent wrong results — abandoned.
// NOTE (r18/r19): dependent global loads inside a barrier-locked main loop
// (per-lane fragment loads, or reg-staged combine) regress 2-4x; the async
// DMA of global_load_lds is the load-bearing property of the staging pattern.
DEVI void pl32swap(unsigned& a, unsigned& b) {
  asm volatile("s_nop 1\nv_permlane32_swap_b32 %0, %1\ns_nop 1"
               : "+v"(a), "+v"(b));
}

#define WAITVM0 asm volatile("s_waitcnt vmcnt(0)" ::: "memory")

// ---------------------------------------------------------------- prep
// Fused ln (blocks 0..4095) + w_qkv transpose (4096..4863) + w_out
// transpose (4864..5119). r13/r14/r17-verified.
__global__ __launch_bounds__(256) void prep_kernel(
    const float* __restrict__ x, const float* __restrict__ gamma,
    const float* __restrict__ beta, __bf16* __restrict__ xn,
    const float* __restrict__ w_qkv, __bf16* __restrict__ wqkvT,
    const float* __restrict__ w_out, __bf16* __restrict__ woutT) {
  __shared__ float tile[64][65];
  __shared__ float red[8];
  int blk = blockIdx.x;
  int t = threadIdx.x;
  if (blk < 4096) {
    int row = blk;
    float4 v = ((const float4*)(x + (size_t)row * 1024))[t];
    float s = v.x + v.y + v.z + v.w;
    float sq = v.x * v.x + v.y * v.y + v.z * v.z + v.w * v.w;
#pragma unroll
    for (int off = 32; off > 0; off >>= 1) {
      s += __shfl_down(s, off);
      sq += __shfl_down(sq, off);
    }
    int w = t >> 6, ln = t & 63;
    if (ln == 0) { red[w] = s; red[4 + w] = sq; }
    __syncthreads();
    s = red[0] + red[1] + red[2] + red[3];
    sq = red[4] + red[5] + red[6] + red[7];
    float mu = s * (1.0f / 1024.0f);
    float var = sq * (1.0f / 1024.0f) - mu * mu;
    float rstd = rsqrtf(var + 1e-5f);
    float4 g = ((const float4*)gamma)[t];
    float4 b = ((const float4*)beta)[t];
    u16x4 o;
    o[0] = bf16_bits((v.x - mu) * rstd * g.x + b.x);
    o[1] = bf16_bits((v.y - mu) * rstd * g.y + b.y);
    o[2] = bf16_bits((v.z - mu) * rstd * g.z + b.z);
    o[3] = bf16_bits((v.w - mu) * rstd * g.w + b.w);
    *(u16x4*)(xn + (size_t)row * 1024 + t * 4) = o;
    return;
  }
  const float* in;
  __bf16* out;
  int R, C, bx, by;
  if (blk < 4096 + 768) {
    int i2 = blk - 4096;
    in = w_qkv; out = wqkvT; R = 1024; C = 3072;
    bx = i2 % 48; by = i2 / 48;
  } else {
    int i3 = blk - 4864;
    in = w_out; out = woutT; R = 1024; C = 1024;
    bx = i3 % 16; by = i3 / 16;
  }
  int tx = t & 15, ty = t >> 4;
  int c0 = bx * 64, r0 = by * 64;
#pragma unroll
  for (int p = 0; p < 4; ++p) {
    int r = ty + p * 16;
    float4 v = *(const float4*)(in + (size_t)(r0 + r) * C + c0 + tx * 4);
    tile[r][tx * 4 + 0] = v.x;
    tile[r][tx * 4 + 1] = v.y;
    tile[r][tx * 4 + 2] = v.z;
    tile[r][tx * 4 + 3] = v.w;
  }
  __syncthreads();
#pragma unroll
  for (int p = 0; p < 4; ++p) {
    int cc = ty + p * 16;
    u16x4 o;
    o[0] = bf16_bits(tile[tx * 4 + 0][cc]);
    o[1] = bf16_bits(tile[tx * 4 + 1][cc]);
    o[2] = bf16_bits(tile[tx * 4 + 2][cc]);
    o[3] = bf16_bits(tile[tx * 4 + 3][cc]);
    *(u16x4*)(out + (size_t)(c0 + cc) * R + r0 + tx * 4) = o;
  }
}

// ---------------------------------------------------------------- QKV GEMM
// r12/r17-verified: 128x128 tile, normal orientation, grid (24,32).
__global__ __launch_bounds__(256) void gemm_qkv_kernel(
    const __bf16* __restrict__ A, const __bf16* __restrict__ BT,
    __bf16* __restrict__ Qb, __bf16* __restrict__ Kb, __bf16* __restrict__ VTb) {
  __shared__ __align__(16) __bf16 Asm[128 * 32];
  __shared__ __align__(16) __bf16 Bsm[128 * 32];
  const int KD = 1024;
  int t = threadIdx.x;
  int w = t >> 6, ln = t & 63;
  int wr = w >> 1, wc = w & 1;
  int m0 = blockIdx.y * 128, n0 = blockIdx.x * 128;
  f32x4 acc[4][4] = {};

  int srow = w * 16 + (ln >> 2);
  int scol = (ln & 3) * 8;
  int lrow = ln & 15;
  int lkb = (ln >> 4) * 16;

  for (int kk = 0; kk < KD; kk += 32) {
    __syncthreads();
#pragma unroll
    for (int i = 0; i < 2; ++i) {
      int row = i * 64 + srow;
      gl_lds16(A + (size_t)(m0 + row) * KD + kk + scol,
               (char*)Asm + i * 4096 + w * 1024);
      gl_lds16(BT + (size_t)(n0 + row) * KD + kk + scol,
               (char*)Bsm + i * 4096 + w * 1024);
    }
    __syncthreads();
    bf16x8 af[4], bfr[4];
#pragma unroll
    for (int mi = 0; mi < 4; ++mi)
      af[mi] = *(const bf16x8*)((char*)Asm + (wr * 64 + mi * 16 + lrow) * 64 + lkb);
#pragma unroll
    for (int ni = 0; ni < 4; ++ni)
      bfr[ni] = *(const bf16x8*)((char*)Bsm + (wc * 64 + ni * 16 + lrow) * 64 + lkb);
#pragma unroll
    for (int mi = 0; mi < 4; ++mi)
#pragma unroll
      for (int ni = 0; ni < 4; ++ni)
        acc[mi][ni] = mfma16x16(af[mi], bfr[ni], acc[mi][ni]);
  }

  int r4 = (ln >> 4) * 4;
#pragma unroll
  for (int mi = 0; mi < 4; ++mi) {
#pragma unroll
    for (int ni = 0; ni < 4; ++ni) {
      int grow = m0 + wr * 64 + mi * 16 + r4;
      int gcol = n0 + wc * 64 + ni * 16 + lrow;
      int sel = gcol >> 10;
      int nl = gcol & 1023;
      int h = nl >> 6, d = nl & 63;
      int b = grow >> 11, seq = grow & 2047;
      int bh = b * 16 + h;
      if (sel < 2) {
        __bf16* dst = (sel == 0 ? Qb : Kb) + ((size_t)bh * 2048 + seq) * 64 + d;
#pragma unroll
        for (int r = 0; r < 4; ++r) dst[(size_t)r * 64] = (__bf16)acc[mi][ni][r];
      } else {
        u16x4 o;
        o[0] = bf16_bits(acc[mi][ni][0]);
        o[1] = bf16_bits(acc[mi][ni][1]);
        o[2] = bf16_bits(acc[mi][ni][2]);
        o[3] = bf16_bits(acc[mi][ni][3]);
        *(u16x4*)(VTb + ((size_t)bh * 64 + d) * 2048 + seq) = o;
      }
    }
  }
}

// ---------------------------------------------------------------- out GEMM
// r12/r17-verified: BM=128 x BN=64, normal orientation, grid (16,32).
__global__ __launch_bounds__(256) void gemm_out_kernel(
    const __bf16* __restrict__ A, const __bf16* __restrict__ BT,
    float* __restrict__ Cout, const float* __restrict__ bias) {
  __shared__ __align__(16) __bf16 Asm[128 * 32];  // 8KB
  __shared__ __align__(16) __bf16 Bsm[64 * 32];   // 4KB
  const int KD = 1024;
  int t = threadIdx.x;
  int w = t >> 6, ln = t & 63;
  int m0 = blockIdx.y * 128, n0 = blockIdx.x * 64;
  f32x4 acc[2][4] = {};

  int srow = w * 16 + (ln >> 2);  // 0..63
  int scol = (ln & 3) * 8;
  int lrow = ln & 15;
  int lkb = (ln >> 4) * 16;

  for (int kk = 0; kk < KD; kk += 32) {
    __syncthreads();
#pragma unroll
    for (int i = 0; i < 2; ++i)
      gl_lds16(A + (size_t)(m0 + i * 64 + srow) * KD + kk + scol,
               (char*)Asm + i * 4096 + w * 1024);
    gl_lds16(BT + (size_t)(n0 + srow) * KD + kk + scol, (char*)Bsm + w * 1024);
    __syncthreads();
    bf16x8 af[2], bfr[4];
#pragma unroll
    for (int mi = 0; mi < 2; ++mi)
      af[mi] = *(const bf16x8*)((char*)Asm + (w * 32 + mi * 16 + lrow) * 64 + lkb);
#pragma unroll
    for (int ni = 0; ni < 4; ++ni)
      bfr[ni] = *(const bf16x8*)((char*)Bsm + (ni * 16 + lrow) * 64 + lkb);
#pragma unroll
    for (int mi = 0; mi < 2; ++mi)
#pragma unroll
      for (int ni = 0; ni < 4; ++ni)
        acc[mi][ni] = mfma16x16(af[mi], bfr[ni], acc[mi][ni]);
  }

  int r4 = (ln >> 4) * 4;
#pragma unroll
  for (int mi = 0; mi < 2; ++mi) {
#pragma unroll
    for (int ni = 0; ni < 4; ++ni) {
      int grow = m0 + w * 32 + mi * 16 + r4;
      int gcol = n0 + ni * 16 + lrow;
      float bv = bias[gcol];
#pragma unroll
      for (int r = 0; r < 4; ++r)
        Cout[(size_t)(grow + r) * 1024 + gcol] = acc[mi][ni][r] + bv;
    }
  }
}

// ---------------------------------------------------------------- attention
// r11/r12/r17-verified: j-SPLIT flash (exact under no-max softmax), grid (16,32,2).
__global__ __launch_bounds__(256, 2) void attn_kernel(
    const __bf16* __restrict__ Qb, const __bf16* __restrict__ Kb,
    const __bf16* __restrict__ VTb, __bf16* __restrict__ Opart,
    float* __restrict__ lbuf) {
  __shared__ __align__(16) char Klds[16384];   // 2 bufs x [64 j][128B], swizzled
  __shared__ __align__(16) char Vlds[16384];   // 2 bufs x [64 d][128B], swizzled
  const float LOG2E = 1.44269504f;
  const float K1 = 0.125f * LOG2E;
  int t = threadIdx.x, w = t >> 6, ln = t & 63;
  int hi = ln >> 5, col = ln & 31;
  int bh = blockIdx.y, bq = bh >> 4, h = bh & 15;
  int q0 = blockIdx.x * 128;
  int jh = blockIdx.z;                 // j-half: tiles jh*16 .. jh*16+15
  const __bf16* Qh = Qb + (size_t)bh * 2048 * 64;
  const __bf16* Kh = Kb + (size_t)bh * 2048 * 64;
  const __bf16* Vh = VTb + (size_t)bh * 64 * 2048;
  __bf16* Oh = Opart + (size_t)jh * 4096 * 1024;  // half = 4M bf16 = 8MB

  bf16x8 qf[4];
  int qrow = q0 + w * 32 + col;
#pragma unroll
  for (int dk = 0; dk < 4; ++dk)
    qf[dk] = *(const bf16x8*)(Qh + (size_t)qrow * 64 + dk * 16 + hi * 8);

  f32x16 oacc0 = {}, oacc1 = {};
  float l_run = 0.f;

  int sj0 = t >> 3, sc0 = (t & 7) ^ (sj0 & 7);
  int sj1 = 32 + (t >> 3), sc1 = (t & 7) ^ (sj1 & 7);

#define STAGE(off, j0_)                                                        \
  do {                                                                         \
    gl_lds16(Kh + (size_t)((j0_) + sj0) * 64 + sc0 * 8, Klds + (off) + w * 1024); \
    gl_lds16(Kh + (size_t)((j0_) + sj1) * 64 + sc1 * 8,                        \
             Klds + (off) + 4096 + w * 1024);                                  \
    gl_lds16(Vh + (size_t)sj0 * 2048 + (j0_) + sc0 * 8, Vlds + (off) + w * 1024); \
    gl_lds16(Vh + (size_t)sj1 * 2048 + (j0_) + sc1 * 8,                        \
             Vlds + (off) + 4096 + w * 1024);                                  \
  } while (0)

  int jbase = jh * 16;
  int cur = 0;
  STAGE(0, jbase * 64);
  WAITVM0;
  __builtin_amdgcn_s_barrier();
  __builtin_amdgcn_sched_barrier(0);

  for (int jt = 0; jt < 16; ++jt) {
    if (jt < 15) STAGE((cur ^ 1) * 8192, (jbase + jt + 1) * 64);
    const char* Kc = Klds + cur * 8192;
    const char* Vc = Vlds + cur * 8192;

    f32x16 sfr0 = {}, sfr1 = {};
#pragma unroll
    for (int dk = 0; dk < 4; ++dk) {
      int sw = ((dk * 32 + hi * 16) ^ ((col & 7) << 4));
      bf16x8 kf0 = *(const bf16x8*)(Kc + col * 128 + sw);
      bf16x8 kf1 = *(const bf16x8*)(Kc + (32 + col) * 128 + sw);
      sfr0 = mfma32(kf0, qf[dk], sfr0);
      sfr1 = mfma32(kf1, qf[dk], sfr1);
    }

    float psum = 0.f;
    bf16x8 pfr[4];
#pragma unroll
    for (int jk = 0; jk < 4; ++jk) {
      float p[8];
#pragma unroll
      for (int c = 0; c < 8; ++c) {
        float sv = (jk < 2) ? sfr0[(jk & 1) * 8 + c] : sfr1[(jk & 1) * 8 + c];
        p[c] = __builtin_amdgcn_exp2f(sv * K1);
      }
      psum += ((p[0] + p[1]) + (p[2] + p[3])) + ((p[4] + p[5]) + (p[6] + p[7]));
      unsigned X0 = cvtpk_bf16(p[0], p[1]);
      unsigned X1 = cvtpk_bf16(p[2], p[3]);
      unsigned Y0 = cvtpk_bf16(p[4], p[5]);
      unsigned Y1 = cvtpk_bf16(p[6], p[7]);
      pl32swap(X0, Y0);
      pl32swap(X1, Y1);
      union { unsigned u[4]; bf16x8 v; } pu;
      pu.u[0] = X0; pu.u[1] = X1; pu.u[2] = Y0; pu.u[3] = Y1;
      pfr[jk] = pu.v;
    }
    l_run += psum;

#pragma unroll
    for (int jk = 0; jk < 4; ++jk) {
      int sw = ((jk * 32 + hi * 16) ^ ((col & 7) << 4));
      bf16x8 vf0 = *(const bf16x8*)(Vc + col * 128 + sw);
      bf16x8 vf1 = *(const bf16x8*)(Vc + (32 + col) * 128 + sw);
      oacc0 = mfma32(vf0, pfr[jk], oacc0);
      oacc1 = mfma32(vf1, pfr[jk], oacc1);
    }

    WAITVM0;
    __builtin_amdgcn_s_barrier();
    __builtin_amdgcn_sched_barrier(0);
    cur ^= 1;
  }
#undef STAGE

  l_run += __shfl_xor(l_run, 32);
  float linv = 1.0f / l_run;
  if (hi == 0)
    lbuf[(((size_t)bh * 16 + blockIdx.x) * 2 + jh) * 128 + w * 32 + col] = l_run;

  char* Ow = Klds + w * 4096;  // [32 i][128B d-row], swizzled
#pragma unroll
  for (int da = 0; da < 2; ++da) {
    const f32x16& oa = da ? oacc1 : oacc0;
#pragma unroll
    for (int g = 0; g < 4; ++g) {
      unsigned w0 = cvtpk_bf16(oa[g * 4 + 0] * linv, oa[g * 4 + 1] * linv);
      unsigned w1 = cvtpk_bf16(oa[g * 4 + 2] * linv, oa[g * 4 + 3] * linv);
      int dby = da * 64 + g * 16 + hi * 8;
      char* dst = Ow + col * 128 + ((dby & ~15) ^ ((col & 7) << 4)) + (dby & 8);
      u32x2 pr = {w0, w1};
      *(u32x2*)dst = pr;
    }
  }
  int rr0 = ln >> 3, c16o = ln & 7;
#pragma unroll
  for (int pp = 0; pp < 4; ++pp) {
    int rr = rr0 + pp * 8;
    bf16x8 ov = *(const bf16x8*)(Ow + rr * 128 + ((c16o * 16) ^ ((rr & 7) << 4)));
    int grow = bq * 2048 + q0 + w * 32 + rr;
    *(bf16x8*)(Oh + (size_t)grow * 1024 + h * 64 + c16o * 8) = ov;
  }
}

// ------------------------------------------------------------- combine
// vectorized — 8 elems (16B)/thread, grid 2048x256 (r12/r17-verified).
__global__ __launch_bounds__(256) void combine_kernel(
    __bf16* __restrict__ O0, const __bf16* __restrict__ O1,
    const float* __restrict__ lbuf) {
  int idx = blockIdx.x * 256 + threadIdx.x;
  int e0 = idx * 8;
  int r = e0 >> 10, c0 = e0 & 1023;
  int b = r >> 11, seq = r & 2047, qb = seq >> 7, i = seq & 127;
  int h = c0 >> 6;
  int bh = b * 16 + h;
  size_t lbase = (((size_t)bh * 16 + qb) * 2) * 128 + i;
  float l0 = lbuf[lbase], l1 = lbuf[lbase + 128];
  float inv = 1.0f / (l0 + l1);
  float w0 = l0 * inv, w1 = l1 * inv;
  bf16x8 a = *(const bf16x8*)(O0 + e0);
  bf16x8 bb = *(const bf16x8*)(O1 + e0);
  unsigned u[4];
#pragma unroll
  for (int j = 0; j < 4; ++j) {
    float lo = w0 * bf16_f32(a[2 * j]) + w1 * bf16_f32(bb[2 * j]);
    float hi2 = w0 * bf16_f32(a[2 * j + 1]) + w1 * bf16_f32(bb[2 * j + 1]);
    u[j] = cvtpk_bf16(lo, hi2);
  }
  union { unsigned uu[4]; bf16x8 v; } pu;
  pu.uu[0] = u[0]; pu.uu[1] = u[1]; pu.uu[2] = u[2]; pu.uu[3] = u[3];
  *(bf16x8*)(O0 + e0) = pu.v;
}

// ---------------------------------------------------------------- launch
extern "C" void kernel_launch(void* const* d_in, const int* in_sizes, int n_in,
                              void* d_out, int out_size, void* d_ws, size_t ws_size,
                              hipStream_t stream) {
  const float* x = (const float*)d_in[0];
  const float* gamma = (const float*)d_in[1];
  const float* beta = (const float*)d_in[2];
  const float* w_qkv = (const float*)d_in[3];
  const float* w_out = (const float*)d_in[4];
  const float* b_out = (const float*)d_in[5];

  char* ws = (char*)d_ws;
  // [0..8): xn / attn half-0 partial / final sa (in-place combine)
  // [8..16): attn half-1 partial
  // [16..22): wqkvT (dead after QKV GEMM; first 1MB reused as lbuf by attn)
  // [22..24): woutT
  // [24..32): Qb   [32..40): Kb   [40..48): VTb
  __bf16* xn = (__bf16*)(ws);
  __bf16* Opart = xn;                               // halves at +0MB / +8MB
  float* lbuf = (float*)(ws + (16l << 20));
  __bf16* wqkvT = (__bf16*)(ws + (16l << 20));
  __bf16* woutT = (__bf16*)(ws + (22l << 20));
  __bf16* Qb = (__bf16*)(ws + (24l << 20));
  __bf16* Kb = (__bf16*)(ws + (32l << 20));
  __bf16* VTb = (__bf16*)(ws + (40l << 20));
  __bf16* sa = xn;  // combine merges half-1 into half-0 in place

  prep_kernel<<<5120, 256, 0, stream>>>(x, gamma, beta, xn, w_qkv, wqkvT,
                                        w_out, woutT);
  gemm_qkv_kernel<<<dim3(24, 32), 256, 0, stream>>>(xn, wqkvT, Qb, Kb, VTb);
  attn_kernel<<<dim3(16, 32, 2), 256, 0, stream>>>(Qb, Kb, VTb, Opart, lbuf);
  combine_kernel<<<2048, 256, 0, stream>>>(sa, Opart + (4096l * 1024), lbuf);
  gemm_out_kernel<<<dim3(16, 32), 256, 0, stream>>>(sa, woutT, (float*)d_out, b_out);
}